// Round 1
// baseline (1024.390 us; speedup 1.0000x reference)
//
#include <hip/hip_runtime.h>
#include <math.h>

#define B_  2
#define W_  2048
#define C_  1024
#define NH_ 16
#define KD_ 64

// ---------------------------------------------------------------------------
// Stage a contiguous 64x64 fp32 tile (row stride 64) into LDS [64][68]
// ---------------------------------------------------------------------------
__device__ __forceinline__ void stage64(const float* __restrict__ src,
                                        float (*dst)[68], int tid) {
#pragma unroll
    for (int q = 0; q < 4; ++q) {
        int idx = tid + (q << 8);       // float4 index 0..1023
        int e   = idx << 2;             // element index
        int r   = e >> 6;
        int c   = e & 63;
        *(float4*)&dst[r][c] = *(const float4*)(src + e);
    }
}

// ---------------------------------------------------------------------------
// GEMM NT:  C[m, c] = sum_k A[m,k] * Bw[c,k] + bias[c]
// A: [4096][1024] row-major, Bw: [1024][1024] row-major (reduction along rows)
// OUT_P_LAYOUT=1: scatter into p_bnwk layout [(b*16+n)][w][k]
// ---------------------------------------------------------------------------
template<int OUT_P_LAYOUT>
__global__ __launch_bounds__(256, 2)
void gemm_nt(const float* __restrict__ A, const float* __restrict__ Bw,
             const float* __restrict__ bias, float* __restrict__ Cout)
{
    __shared__ float As[16][68];
    __shared__ float Bs[16][68];
    const int tid = threadIdx.x;
    const int tx  = tid & 15, ty = tid >> 4;
    const int m0  = blockIdx.x << 6;
    const int n0  = blockIdx.y << 6;
    const int lrow = tid >> 2;           // 0..63
    const int lkq  = (tid & 3) << 2;     // 0,4,8,12
    const float* Ap = A  + (size_t)(m0 + lrow) * C_ + lkq;
    const float* Bp = Bw + (size_t)(n0 + lrow) * C_ + lkq;

    float acc[4][4] = {};
    for (int k0 = 0; k0 < C_; k0 += 16) {
        float4 av = *(const float4*)(Ap + k0);
        float4 bv = *(const float4*)(Bp + k0);
        __syncthreads();
        As[lkq+0][lrow] = av.x; As[lkq+1][lrow] = av.y;
        As[lkq+2][lrow] = av.z; As[lkq+3][lrow] = av.w;
        Bs[lkq+0][lrow] = bv.x; Bs[lkq+1][lrow] = bv.y;
        Bs[lkq+2][lrow] = bv.z; Bs[lkq+3][lrow] = bv.w;
        __syncthreads();
#pragma unroll
        for (int kk = 0; kk < 16; ++kk) {
            float4 a4 = *(const float4*)&As[kk][ty << 2];
            float4 b4 = *(const float4*)&Bs[kk][tx << 2];
            float am[4] = {a4.x, a4.y, a4.z, a4.w};
            float bm[4] = {b4.x, b4.y, b4.z, b4.w};
#pragma unroll
            for (int i = 0; i < 4; ++i)
#pragma unroll
                for (int j = 0; j < 4; ++j)
                    acc[i][j] = fmaf(am[i], bm[j], acc[i][j]);
        }
    }

    const int gc = n0 + (tx << 2);
    float4 bb = *(const float4*)&bias[gc];
#pragma unroll
    for (int i = 0; i < 4; ++i) {
        int gm = m0 + (ty << 2) + i;
        float4 o;
        o.x = acc[i][0] + bb.x;
        o.y = acc[i][1] + bb.y;
        o.z = acc[i][2] + bb.z;
        o.w = acc[i][3] + bb.w;
        if (OUT_P_LAYOUT) {
            int b = gm >> 11;        // / 2048
            int w = gm & 2047;
            int n = gc >> 6;
            int k = gc & 63;
            *(float4*)(Cout + (((size_t)(b * NH_ + n) * W_ + w) * KD_ + k)) = o;
        } else {
            *(float4*)(Cout + (size_t)gm * C_ + gc) = o;
        }
    }
}

// ---------------------------------------------------------------------------
// Per (b,n):  M1[k][l] = sum_w p[bn][w][k] * g[n][w][l]   (K-dim = 2048)
//             M1 = tril(M1);  M2 = M1 @ M1^T
// One workgroup per bn (32 blocks).
// ---------------------------------------------------------------------------
__global__ __launch_bounds__(256, 2)
void metric_k(const float* __restrict__ p, const float* __restrict__ g,
              float* __restrict__ m2)
{
    __shared__ float Ps[32][68];
    __shared__ float Gs[32][68];
    __shared__ float M1s[64][68];
    const int bn  = blockIdx.x;
    const int n   = bn & (NH_ - 1);
    const int tid = threadIdx.x;
    const int tx  = tid & 15, ty = tid >> 4;
    const float* pb = p + (size_t)bn * W_ * KD_;
    const float* gb = g + (size_t)n  * W_ * KD_;

    float acc[4][4] = {};
    for (int w0 = 0; w0 < W_; w0 += 32) {
        __syncthreads();
#pragma unroll
        for (int q = 0; q < 2; ++q) {
            int idx = tid + (q << 8);     // float4 index 0..511
            int e   = idx << 2;
            int r   = e >> 6;
            int c   = e & 63;
            *(float4*)&Ps[r][c] = *(const float4*)(pb + (size_t)(w0 + r) * KD_ + c);
            *(float4*)&Gs[r][c] = *(const float4*)(gb + (size_t)(w0 + r) * KD_ + c);
        }
        __syncthreads();
#pragma unroll 8
        for (int w = 0; w < 32; ++w) {
            float4 a4 = *(const float4*)&Ps[w][ty << 2];
            float4 b4 = *(const float4*)&Gs[w][tx << 2];
            float am[4] = {a4.x, a4.y, a4.z, a4.w};
            float bm[4] = {b4.x, b4.y, b4.z, b4.w};
#pragma unroll
            for (int i = 0; i < 4; ++i)
#pragma unroll
                for (int j = 0; j < 4; ++j)
                    acc[i][j] = fmaf(am[i], bm[j], acc[i][j]);
        }
    }

    __syncthreads();
#pragma unroll
    for (int i = 0; i < 4; ++i)
#pragma unroll
        for (int j = 0; j < 4; ++j) {
            int k = (ty << 2) + i, l = (tx << 2) + j;
            M1s[k][l] = (l <= k) ? acc[i][j] : 0.f;
        }
    __syncthreads();

    float a2[4][4] = {};
#pragma unroll
    for (int jq = 0; jq < 64; jq += 4) {
        float4 av[4], bv[4];
#pragma unroll
        for (int i = 0; i < 4; ++i) av[i] = *(const float4*)&M1s[(ty << 2) + i][jq];
#pragma unroll
        for (int j = 0; j < 4; ++j) bv[j] = *(const float4*)&M1s[(tx << 2) + j][jq];
#pragma unroll
        for (int i = 0; i < 4; ++i)
#pragma unroll
            for (int j = 0; j < 4; ++j)
                a2[i][j] += av[i].x * bv[j].x + av[i].y * bv[j].y +
                            av[i].z * bv[j].z + av[i].w * bv[j].w;
    }

    float* ob = m2 + (size_t)bn * KD_ * KD_;
#pragma unroll
    for (int i = 0; i < 4; ++i) {
        float4 o; o.x = a2[i][0]; o.y = a2[i][1]; o.z = a2[i][2]; o.w = a2[i][3];
        *(float4*)(ob + ((ty << 2) + i) * KD_ + (tx << 2)) = o;
    }
}

// ---------------------------------------------------------------------------
// Q[bn][w][l] = (1/8) * sum_k p[bn][w][k] * M2[bn][k][l]
// Grid: (W/64, 32)
// ---------------------------------------------------------------------------
__global__ __launch_bounds__(256, 2)
void qgen_k(const float* __restrict__ p, const float* __restrict__ m2,
            float* __restrict__ qout)
{
    __shared__ float Pt[64][68];
    __shared__ float Ms[64][68];
    const int bn  = blockIdx.y;
    const int w0  = blockIdx.x << 6;
    const int tid = threadIdx.x;
    const int tx  = tid & 15, ty = tid >> 4;
    const float* pb = p  + (size_t)bn * W_ * KD_ + (size_t)w0 * KD_;
    const float* mb = m2 + (size_t)bn * KD_ * KD_;

    stage64(pb, Pt, tid);
    stage64(mb, Ms, tid);
    __syncthreads();

    float acc[4][4] = {};
#pragma unroll
    for (int kq = 0; kq < 64; kq += 4) {
        float4 av[4];
        float  bm[4][4];
#pragma unroll
        for (int i = 0; i < 4; ++i) av[i] = *(const float4*)&Pt[(ty << 2) + i][kq];
#pragma unroll
        for (int kk = 0; kk < 4; ++kk) {
            float4 t = *(const float4*)&Ms[kq + kk][tx << 2];
            bm[kk][0] = t.x; bm[kk][1] = t.y; bm[kk][2] = t.z; bm[kk][3] = t.w;
        }
#pragma unroll
        for (int i = 0; i < 4; ++i) {
            float am[4] = {av[i].x, av[i].y, av[i].z, av[i].w};
#pragma unroll
            for (int j = 0; j < 4; ++j)
                acc[i][j] = fmaf(am[0], bm[0][j],
                            fmaf(am[1], bm[1][j],
                            fmaf(am[2], bm[2][j],
                            fmaf(am[3], bm[3][j], acc[i][j]))));
        }
    }

    float* ob = qout + (size_t)bn * W_ * KD_ + (size_t)w0 * KD_;
#pragma unroll
    for (int i = 0; i < 4; ++i) {
        float4 o;
        o.x = acc[i][0] * 0.125f; o.y = acc[i][1] * 0.125f;
        o.z = acc[i][2] * 0.125f; o.w = acc[i][3] * 0.125f;
        *(float4*)(ob + ((ty << 2) + i) * KD_ + (tx << 2)) = o;
    }
}

// ---------------------------------------------------------------------------
// Causal flash attention per (b,n): q = Q (pre-scaled), k = v = P.
// Out: nudged in [b][w][n*64+k] layout ([4096][1024]).
// Grid: (qtile 32, bn 32)
// ---------------------------------------------------------------------------
__global__ __launch_bounds__(256, 2)
void attn_k(const float* __restrict__ qg, const float* __restrict__ p,
            float* __restrict__ nud)
{
    __shared__ float Qs[64][68];
    __shared__ float Ks[64][68];
    __shared__ float Es[64][68];
    const int qt  = blockIdx.x;
    const int bn  = blockIdx.y;
    const int b   = bn >> 4, n = bn & 15;
    const int tid = threadIdx.x;
    const int tx  = tid & 15, ty = tid >> 4;
    const float* qb = qg + (size_t)bn * W_ * KD_ + (size_t)(qt << 6) * KD_;
    const float* kb = p  + (size_t)bn * W_ * KD_;

    stage64(qb, Qs, tid);

    float acc[4][4] = {};
    float mi[4], li[4];
#pragma unroll
    for (int i = 0; i < 4; ++i) { mi[i] = -INFINITY; li[i] = 0.f; }

    for (int j0 = 0; j0 <= qt; ++j0) {
        __syncthreads();   // protects Ks/Es reuse + first-iter Qs staging
        stage64(kb + (size_t)(j0 << 6) * KD_, Ks, tid);
        __syncthreads();

        // S = Qs @ Ks^T  (4x4 per thread)
        float s[4][4] = {};
#pragma unroll
        for (int kq = 0; kq < 64; kq += 4) {
            float4 av[4], bv[4];
#pragma unroll
            for (int i = 0; i < 4; ++i) av[i] = *(const float4*)&Qs[(ty << 2) + i][kq];
#pragma unroll
            for (int j = 0; j < 4; ++j) bv[j] = *(const float4*)&Ks[(tx << 2) + j][kq];
#pragma unroll
            for (int i = 0; i < 4; ++i)
#pragma unroll
                for (int j = 0; j < 4; ++j)
                    s[i][j] = fmaf(av[i].x, bv[j].x,
                              fmaf(av[i].y, bv[j].y,
                              fmaf(av[i].z, bv[j].z,
                              fmaf(av[i].w, bv[j].w, s[i][j]))));
        }

        if (j0 == qt) {
#pragma unroll
            for (int i = 0; i < 4; ++i)
#pragma unroll
                for (int j = 0; j < 4; ++j)
                    if (((tx << 2) + j) > ((ty << 2) + i)) s[i][j] = -INFINITY;
        }

        float mnew[4], al[4];
#pragma unroll
        for (int i = 0; i < 4; ++i) {
            float rm = fmaxf(fmaxf(s[i][0], s[i][1]), fmaxf(s[i][2], s[i][3]));
            rm = fmaxf(rm, __shfl_xor(rm, 1, 16));
            rm = fmaxf(rm, __shfl_xor(rm, 2, 16));
            rm = fmaxf(rm, __shfl_xor(rm, 4, 16));
            rm = fmaxf(rm, __shfl_xor(rm, 8, 16));
            mnew[i] = fmaxf(mi[i], rm);
        }
#pragma unroll
        for (int i = 0; i < 4; ++i) {
#pragma unroll
            for (int j = 0; j < 4; ++j) s[i][j] = __expf(s[i][j] - mnew[i]);
            float rs = s[i][0] + s[i][1] + s[i][2] + s[i][3];
            rs += __shfl_xor(rs, 1, 16);
            rs += __shfl_xor(rs, 2, 16);
            rs += __shfl_xor(rs, 4, 16);
            rs += __shfl_xor(rs, 8, 16);
            al[i] = __expf(mi[i] - mnew[i]);
            li[i] = li[i] * al[i] + rs;
            mi[i] = mnew[i];
        }
#pragma unroll
        for (int i = 0; i < 4; ++i)
#pragma unroll
            for (int j = 0; j < 4; ++j) {
                Es[(ty << 2) + i][(tx << 2) + j] = s[i][j];
                acc[i][j] *= al[i];
            }
        __syncthreads();

        // O += Es @ Ks   (V = K tile)
#pragma unroll
        for (int jq = 0; jq < 64; jq += 4) {
            float4 av[4];
            float  vm[4][4];
#pragma unroll
            for (int i = 0; i < 4; ++i) av[i] = *(const float4*)&Es[(ty << 2) + i][jq];
#pragma unroll
            for (int kk = 0; kk < 4; ++kk) {
                float4 t = *(const float4*)&Ks[jq + kk][tx << 2];
                vm[kk][0] = t.x; vm[kk][1] = t.y; vm[kk][2] = t.z; vm[kk][3] = t.w;
            }
#pragma unroll
            for (int i = 0; i < 4; ++i) {
                float am[4] = {av[i].x, av[i].y, av[i].z, av[i].w};
#pragma unroll
                for (int c = 0; c < 4; ++c)
                    acc[i][c] = fmaf(am[0], vm[0][c],
                                fmaf(am[1], vm[1][c],
                                fmaf(am[2], vm[2][c],
                                fmaf(am[3], vm[3][c], acc[i][c]))));
            }
        }
    }

    const int wrow = qt << 6;
#pragma unroll
    for (int i = 0; i < 4; ++i) {
        float inv = 1.f / li[i];
        float4 o;
        o.x = acc[i][0] * inv; o.y = acc[i][1] * inv;
        o.z = acc[i][2] * inv; o.w = acc[i][3] * inv;
        size_t row = (size_t)(b * W_ + wrow + (ty << 2) + i);
        *(float4*)(nud + row * C_ + (n << 6) + (tx << 2)) = o;
    }
}

// ---------------------------------------------------------------------------
extern "C" void kernel_launch(void* const* d_in, const int* in_sizes, int n_in,
                              void* d_out, int out_size, void* d_ws, size_t ws_size,
                              hipStream_t stream)
{
    (void)in_sizes; (void)n_in; (void)out_size; (void)ws_size;
    const float* X  = (const float*)d_in[0];   // (2,2048,1024)
    const float* Wp = (const float*)d_in[1];   // (1024,1024)
    const float* bp = (const float*)d_in[2];   // (1024,)
    const float* G  = (const float*)d_in[3];   // (1,16,2048,64)
    const float* Wm = (const float*)d_in[4];   // (1024,1024)
    const float* bm = (const float*)d_in[5];   // (1024,)
    float* out = (float*)d_out;                // (2,2048,1024)
    float* ws  = (float*)d_ws;

    float* Pbuf = ws;                // 4194304 floats  [bn][w][k]
    float* Qbuf = ws + 4194304;      // 4194304 floats  [bn][w][k]
    float* M2   = ws + 8388608;      // 131072 floats   [bn][k][l]
    float* Nud  = ws + 8519680;      // 4194304 floats  [b*W+w][c]

    dim3 blk(256);
    gemm_nt<1><<<dim3(64, 16), blk, 0, stream>>>(X, Wp, bp, Pbuf);
    metric_k  <<<dim3(32),     blk, 0, stream>>>(Pbuf, G, M2);
    qgen_k    <<<dim3(32, 32), blk, 0, stream>>>(Pbuf, M2, Qbuf);
    attn_k    <<<dim3(32, 32), blk, 0, stream>>>(Qbuf, Pbuf, Nud);
    gemm_nt<0><<<dim3(64, 16), blk, 0, stream>>>(Nud, Wm, bm, out);
}

// Round 2
// 842.586 us; speedup vs baseline: 1.2158x; 1.2158x over previous
//
#include <hip/hip_runtime.h>
#include <math.h>

#define B_  2
#define W_  2048
#define C_  1024
#define NH_ 16
#define KD_ 64

// ---------------------------------------------------------------------------
// XOR-swizzled 64x64 fp32 tile in flat float[4096].
// float4 chunk q of row r lives at slot q ^ ((r>>2)&7).
// Strided-row reads (row stride 4) spread over all 8 bank groups (2-way, free);
// row-fixed chunk-varying reads are permutations (free).
// ---------------------------------------------------------------------------
__device__ __forceinline__ int sw(int r, int c) {   // c must be 0 mod 4
    return (r << 6) + ((((c >> 2) ^ ((r >> 2) & 7)) << 2) | (c & 3));
}

__device__ __forceinline__ void stage64s(const float* __restrict__ src,
                                         float* dst, int tid) {
#pragma unroll
    for (int q = 0; q < 4; ++q) {
        int idx = tid + (q << 8);        // float4 index 0..1023
        int r   = idx >> 4;
        int c   = (idx & 15) << 2;
        *(float4*)&dst[sw(r, c)] = *(const float4*)(src + (idx << 2));
    }
}

// Padded staging used by qgen (patterns there are conflict-free already)
__device__ __forceinline__ void stage64(const float* __restrict__ src,
                                        float (*dst)[68], int tid) {
#pragma unroll
    for (int q = 0; q < 4; ++q) {
        int idx = tid + (q << 8);
        int e   = idx << 2;
        int r   = e >> 6;
        int c   = e & 63;
        *(float4*)&dst[r][c] = *(const float4*)(src + e);
    }
}

// ---------------------------------------------------------------------------
// GEMM NT:  C[m, c] = sum_k A[m,k] * Bw[c,k] + bias[c]
// ---------------------------------------------------------------------------
template<int OUT_P_LAYOUT>
__global__ __launch_bounds__(256, 2)
void gemm_nt(const float* __restrict__ A, const float* __restrict__ Bw,
             const float* __restrict__ bias, float* __restrict__ Cout)
{
    __shared__ float As[16][68];
    __shared__ float Bs[16][68];
    const int tid = threadIdx.x;
    const int tx  = tid & 15, ty = tid >> 4;
    const int m0  = blockIdx.x << 6;
    const int n0  = blockIdx.y << 6;
    const int lrow = tid >> 2;
    const int lkq  = (tid & 3) << 2;
    const float* Ap = A  + (size_t)(m0 + lrow) * C_ + lkq;
    const float* Bp = Bw + (size_t)(n0 + lrow) * C_ + lkq;

    float acc[4][4] = {};
    for (int k0 = 0; k0 < C_; k0 += 16) {
        float4 av = *(const float4*)(Ap + k0);
        float4 bv = *(const float4*)(Bp + k0);
        __syncthreads();
        As[lkq+0][lrow] = av.x; As[lkq+1][lrow] = av.y;
        As[lkq+2][lrow] = av.z; As[lkq+3][lrow] = av.w;
        Bs[lkq+0][lrow] = bv.x; Bs[lkq+1][lrow] = bv.y;
        Bs[lkq+2][lrow] = bv.z; Bs[lkq+3][lrow] = bv.w;
        __syncthreads();
#pragma unroll
        for (int kk = 0; kk < 16; ++kk) {
            float4 a4 = *(const float4*)&As[kk][ty << 2];
            float4 b4 = *(const float4*)&Bs[kk][tx << 2];
            float am[4] = {a4.x, a4.y, a4.z, a4.w};
            float bm[4] = {b4.x, b4.y, b4.z, b4.w};
#pragma unroll
            for (int i = 0; i < 4; ++i)
#pragma unroll
                for (int j = 0; j < 4; ++j)
                    acc[i][j] = fmaf(am[i], bm[j], acc[i][j]);
        }
    }

    const int gc = n0 + (tx << 2);
    float4 bb = *(const float4*)&bias[gc];
#pragma unroll
    for (int i = 0; i < 4; ++i) {
        int gm = m0 + (ty << 2) + i;
        float4 o;
        o.x = acc[i][0] + bb.x;
        o.y = acc[i][1] + bb.y;
        o.z = acc[i][2] + bb.z;
        o.w = acc[i][3] + bb.w;
        if (OUT_P_LAYOUT) {
            int b = gm >> 11;
            int w = gm & 2047;
            int n = gc >> 6;
            int k = gc & 63;
            *(float4*)(Cout + (((size_t)(b * NH_ + n) * W_ + w) * KD_ + k)) = o;
        } else {
            *(float4*)(Cout + (size_t)gm * C_ + gc) = o;
        }
    }
}

// ---------------------------------------------------------------------------
// metric_part: partial M1[k][l] = sum_{w in chunk} p[bn][w][k] * g[n][w][l]
// Grid: (8 chunks, 32 bn). Output part[(bn*8+chunk)][64][64].
// ---------------------------------------------------------------------------
__global__ __launch_bounds__(256, 2)
void metric_part(const float* __restrict__ p, const float* __restrict__ g,
                 float* __restrict__ part)
{
    __shared__ float Ps[32][68];
    __shared__ float Gs[32][68];
    const int ch  = blockIdx.x;
    const int bn  = blockIdx.y;
    const int n   = bn & (NH_ - 1);
    const int tid = threadIdx.x;
    const int tx  = tid & 15, ty = tid >> 4;
    const float* pb = p + (size_t)bn * W_ * KD_ + (size_t)(ch << 8) * KD_;
    const float* gb = g + (size_t)n  * W_ * KD_ + (size_t)(ch << 8) * KD_;

    float acc[4][4] = {};
    for (int w0 = 0; w0 < 256; w0 += 32) {
        __syncthreads();
#pragma unroll
        for (int q = 0; q < 2; ++q) {
            int idx = tid + (q << 8);
            int e   = idx << 2;
            int r   = e >> 6;
            int c   = e & 63;
            *(float4*)&Ps[r][c] = *(const float4*)(pb + (size_t)(w0 + r) * KD_ + c);
            *(float4*)&Gs[r][c] = *(const float4*)(gb + (size_t)(w0 + r) * KD_ + c);
        }
        __syncthreads();
#pragma unroll 8
        for (int w = 0; w < 32; ++w) {
            float4 a4 = *(const float4*)&Ps[w][ty << 2];
            float4 b4 = *(const float4*)&Gs[w][tx << 2];
            float am[4] = {a4.x, a4.y, a4.z, a4.w};
            float bm[4] = {b4.x, b4.y, b4.z, b4.w};
#pragma unroll
            for (int i = 0; i < 4; ++i)
#pragma unroll
                for (int j = 0; j < 4; ++j)
                    acc[i][j] = fmaf(am[i], bm[j], acc[i][j]);
        }
    }

    float* ob = part + (size_t)(bn * 8 + ch) * KD_ * KD_;
#pragma unroll
    for (int i = 0; i < 4; ++i) {
        float4 o; o.x = acc[i][0]; o.y = acc[i][1]; o.z = acc[i][2]; o.w = acc[i][3];
        *(float4*)(ob + ((ty << 2) + i) * KD_ + (tx << 2)) = o;
    }
}

// ---------------------------------------------------------------------------
// metric_reduce: M1 = tril(sum_ch part);  M2 = M1 @ M1^T.  Grid: 32 blocks.
// ---------------------------------------------------------------------------
__global__ __launch_bounds__(256, 2)
void metric_reduce(const float* __restrict__ part, float* __restrict__ m2)
{
    __shared__ float M1s[64][68];
    const int bn  = blockIdx.x;
    const int tid = threadIdx.x;
    const int tx  = tid & 15, ty = tid >> 4;
    const float* pb = part + (size_t)bn * 8 * KD_ * KD_;

#pragma unroll
    for (int v = 0; v < 4; ++v) {
        int f = tid + (v << 8);          // float4 index 0..1023
        int e = f << 2;
        float4 s = *(const float4*)(pb + e);
#pragma unroll
        for (int c = 1; c < 8; ++c) {
            float4 t = *(const float4*)(pb + c * 4096 + e);
            s.x += t.x; s.y += t.y; s.z += t.z; s.w += t.w;
        }
        int k = e >> 6, l = e & 63;
        if (l + 0 > k) s.x = 0.f;
        if (l + 1 > k) s.y = 0.f;
        if (l + 2 > k) s.z = 0.f;
        if (l + 3 > k) s.w = 0.f;
        *(float4*)&M1s[k][l] = s;
    }
    __syncthreads();

    float a2[4][4] = {};
#pragma unroll
    for (int jq = 0; jq < 64; jq += 4) {
        float4 av[4], bv[4];
#pragma unroll
        for (int i = 0; i < 4; ++i) av[i] = *(const float4*)&M1s[(ty << 2) + i][jq];
#pragma unroll
        for (int j = 0; j < 4; ++j) bv[j] = *(const float4*)&M1s[(tx << 2) + j][jq];
#pragma unroll
        for (int i = 0; i < 4; ++i)
#pragma unroll
            for (int j = 0; j < 4; ++j)
                a2[i][j] += av[i].x * bv[j].x + av[i].y * bv[j].y +
                            av[i].z * bv[j].z + av[i].w * bv[j].w;
    }

    float* ob = m2 + (size_t)bn * KD_ * KD_;
#pragma unroll
    for (int i = 0; i < 4; ++i) {
        float4 o; o.x = a2[i][0]; o.y = a2[i][1]; o.z = a2[i][2]; o.w = a2[i][3];
        *(float4*)(ob + ((ty << 2) + i) * KD_ + (tx << 2)) = o;
    }
}

// ---------------------------------------------------------------------------
// Q[bn][w][l] = (1/8) * sum_k p[bn][w][k] * M2[bn][k][l]
// ---------------------------------------------------------------------------
__global__ __launch_bounds__(256, 2)
void qgen_k(const float* __restrict__ p, const float* __restrict__ m2,
            float* __restrict__ qout)
{
    __shared__ float Pt[64][68];
    __shared__ float Ms[64][68];
    const int bn  = blockIdx.y;
    const int w0  = blockIdx.x << 6;
    const int tid = threadIdx.x;
    const int tx  = tid & 15, ty = tid >> 4;
    const float* pb = p  + (size_t)bn * W_ * KD_ + (size_t)w0 * KD_;
    const float* mb = m2 + (size_t)bn * KD_ * KD_;

    stage64(pb, Pt, tid);
    stage64(mb, Ms, tid);
    __syncthreads();

    float acc[4][4] = {};
#pragma unroll
    for (int kq = 0; kq < 64; kq += 4) {
        float4 av[4];
        float  bm[4][4];
#pragma unroll
        for (int i = 0; i < 4; ++i) av[i] = *(const float4*)&Pt[(ty << 2) + i][kq];
#pragma unroll
        for (int kk = 0; kk < 4; ++kk) {
            float4 t = *(const float4*)&Ms[kq + kk][tx << 2];
            bm[kk][0] = t.x; bm[kk][1] = t.y; bm[kk][2] = t.z; bm[kk][3] = t.w;
        }
#pragma unroll
        for (int i = 0; i < 4; ++i) {
            float am[4] = {av[i].x, av[i].y, av[i].z, av[i].w};
#pragma unroll
            for (int j = 0; j < 4; ++j)
                acc[i][j] = fmaf(am[0], bm[0][j],
                            fmaf(am[1], bm[1][j],
                            fmaf(am[2], bm[2][j],
                            fmaf(am[3], bm[3][j], acc[i][j]))));
        }
    }

    float* ob = qout + (size_t)bn * W_ * KD_ + (size_t)w0 * KD_;
#pragma unroll
    for (int i = 0; i < 4; ++i) {
        float4 o;
        o.x = acc[i][0] * 0.125f; o.y = acc[i][1] * 0.125f;
        o.z = acc[i][2] * 0.125f; o.w = acc[i][3] * 0.125f;
        *(float4*)(ob + ((ty << 2) + i) * KD_ + (tx << 2)) = o;
    }
}

// ---------------------------------------------------------------------------
// Causal flash attention per (b,n): q = Q (pre-scaled), k = v = P.
// Swizzled LDS tiles; blocks dispatched in DESCENDING cost order.
// Grid: 1024 blocks 1D: bn = bid & 31, qt = 31 - (bid >> 5).
// ---------------------------------------------------------------------------
__global__ __launch_bounds__(256, 2)
void attn_k(const float* __restrict__ qg, const float* __restrict__ p,
            float* __restrict__ nud)
{
    __shared__ float Qs[4096];
    __shared__ float Ks[4096];
    __shared__ float Es[4096];
    const int bid = blockIdx.x;
    const int bn  = bid & 31;
    const int qt  = 31 - (bid >> 5);     // expensive q-tiles dispatch first
    const int b   = bn >> 4, n = bn & 15;
    const int tid = threadIdx.x;
    const int tx  = tid & 15, ty = tid >> 4;
    const float* qb = qg + (size_t)bn * W_ * KD_ + (size_t)(qt << 6) * KD_;
    const float* kb = p  + (size_t)bn * W_ * KD_;

    stage64s(qb, Qs, tid);

    float acc[4][4] = {};
    float mi[4], li[4];
#pragma unroll
    for (int i = 0; i < 4; ++i) { mi[i] = -INFINITY; li[i] = 0.f; }

    for (int j0 = 0; j0 <= qt; ++j0) {
        __syncthreads();   // prev PV done with Ks/Es; also first-iter Qs staging
        stage64s(kb + (size_t)(j0 << 6) * KD_, Ks, tid);
        __syncthreads();

        // S = Qs @ Ks^T
        float s[4][4] = {};
#pragma unroll
        for (int kq = 0; kq < 64; kq += 4) {
            float4 av[4], bv[4];
#pragma unroll
            for (int i = 0; i < 4; ++i) av[i] = *(const float4*)&Qs[sw((ty << 2) + i, kq)];
#pragma unroll
            for (int j = 0; j < 4; ++j) bv[j] = *(const float4*)&Ks[sw((tx << 2) + j, kq)];
#pragma unroll
            for (int i = 0; i < 4; ++i)
#pragma unroll
                for (int j = 0; j < 4; ++j)
                    s[i][j] = fmaf(av[i].x, bv[j].x,
                              fmaf(av[i].y, bv[j].y,
                              fmaf(av[i].z, bv[j].z,
                              fmaf(av[i].w, bv[j].w, s[i][j]))));
        }

        if (j0 == qt) {
#pragma unroll
            for (int i = 0; i < 4; ++i)
#pragma unroll
                for (int j = 0; j < 4; ++j)
                    if (((tx << 2) + j) > ((ty << 2) + i)) s[i][j] = -INFINITY;
        }

        float mnew[4], al[4];
#pragma unroll
        for (int i = 0; i < 4; ++i) {
            float rm = fmaxf(fmaxf(s[i][0], s[i][1]), fmaxf(s[i][2], s[i][3]));
            rm = fmaxf(rm, __shfl_xor(rm, 1, 16));
            rm = fmaxf(rm, __shfl_xor(rm, 2, 16));
            rm = fmaxf(rm, __shfl_xor(rm, 4, 16));
            rm = fmaxf(rm, __shfl_xor(rm, 8, 16));
            mnew[i] = fmaxf(mi[i], rm);
        }
#pragma unroll
        for (int i = 0; i < 4; ++i) {
#pragma unroll
            for (int j = 0; j < 4; ++j) s[i][j] = __expf(s[i][j] - mnew[i]);
            float rs = s[i][0] + s[i][1] + s[i][2] + s[i][3];
            rs += __shfl_xor(rs, 1, 16);
            rs += __shfl_xor(rs, 2, 16);
            rs += __shfl_xor(rs, 4, 16);
            rs += __shfl_xor(rs, 8, 16);
            al[i] = __expf(mi[i] - mnew[i]);
            li[i] = li[i] * al[i] + rs;
            mi[i] = mnew[i];
        }
#pragma unroll
        for (int i = 0; i < 4; ++i) {
            float4 e; e.x = s[i][0]; e.y = s[i][1]; e.z = s[i][2]; e.w = s[i][3];
            *(float4*)&Es[sw((ty << 2) + i, tx << 2)] = e;
#pragma unroll
            for (int j = 0; j < 4; ++j) acc[i][j] *= al[i];
        }
        __syncthreads();

        // O += Es @ Ks   (V = K tile)
#pragma unroll
        for (int jq = 0; jq < 64; jq += 4) {
            float4 av[4];
            float  vm[4][4];
#pragma unroll
            for (int i = 0; i < 4; ++i) av[i] = *(const float4*)&Es[sw((ty << 2) + i, jq)];
#pragma unroll
            for (int kk = 0; kk < 4; ++kk) {
                float4 t = *(const float4*)&Ks[sw(jq + kk, tx << 2)];
                vm[kk][0] = t.x; vm[kk][1] = t.y; vm[kk][2] = t.z; vm[kk][3] = t.w;
            }
#pragma unroll
            for (int i = 0; i < 4; ++i) {
                float am[4] = {av[i].x, av[i].y, av[i].z, av[i].w};
#pragma unroll
                for (int c = 0; c < 4; ++c)
                    acc[i][c] = fmaf(am[0], vm[0][c],
                                fmaf(am[1], vm[1][c],
                                fmaf(am[2], vm[2][c],
                                fmaf(am[3], vm[3][c], acc[i][c]))));
            }
        }
    }

    const int wrow = qt << 6;
#pragma unroll
    for (int i = 0; i < 4; ++i) {
        float inv = 1.f / li[i];
        float4 o;
        o.x = acc[i][0] * inv; o.y = acc[i][1] * inv;
        o.z = acc[i][2] * inv; o.w = acc[i][3] * inv;
        size_t row = (size_t)(b * W_ + wrow + (ty << 2) + i);
        *(float4*)(nud + row * C_ + (n << 6) + (tx << 2)) = o;
    }
}

// ---------------------------------------------------------------------------
extern "C" void kernel_launch(void* const* d_in, const int* in_sizes, int n_in,
                              void* d_out, int out_size, void* d_ws, size_t ws_size,
                              hipStream_t stream)
{
    (void)in_sizes; (void)n_in; (void)out_size; (void)ws_size;
    const float* X  = (const float*)d_in[0];   // (2,2048,1024)
    const float* Wp = (const float*)d_in[1];   // (1024,1024)
    const float* bp = (const float*)d_in[2];   // (1024,)
    const float* G  = (const float*)d_in[3];   // (1,16,2048,64)
    const float* Wm = (const float*)d_in[4];   // (1024,1024)
    const float* bm = (const float*)d_in[5];   // (1024,)
    float* out = (float*)d_out;                // (2,2048,1024)
    float* ws  = (float*)d_ws;

    float* Pbuf = ws;                // 4194304 floats  [bn][w][k]
    float* Qbuf = ws + 4194304;      // 4194304 floats  [bn][w][k]
    float* M2   = ws + 8388608;      // 131072 floats   [bn][k][l]
    float* Nud  = ws + 8519680;      // 4194304 floats  [b*W+w][c]
    // metric partials overlay Qbuf (dead until qgen_k writes it):
    float* Part = Qbuf;              // 32*8*4096 = 1048576 floats

    dim3 blk(256);
    gemm_nt<1>   <<<dim3(64, 16), blk, 0, stream>>>(X, Wp, bp, Pbuf);
    metric_part  <<<dim3(8, 32),  blk, 0, stream>>>(Pbuf, G, Part);
    metric_reduce<<<dim3(32),     blk, 0, stream>>>(Part, M2);
    qgen_k       <<<dim3(32, 32), blk, 0, stream>>>(Pbuf, M2, Qbuf);
    attn_k       <<<dim3(1024),   blk, 0, stream>>>(Qbuf, Pbuf, Nud);
    gemm_nt<0>   <<<dim3(64, 16), blk, 0, stream>>>(Nud, Wm, bm, out);
}